// Round 2
// baseline (264.293 us; speedup 1.0000x reference)
//
#include <hip/hip_runtime.h>
#include <hip/hip_bf16.h>

typedef __bf16 bf16x8 __attribute__((ext_vector_type(8)));
typedef float  f32x4  __attribute__((ext_vector_type(4)));
typedef float  f32x16 __attribute__((ext_vector_type(16)));

static constexpr int S  = 64;    // DIM_S
static constexpr int C  = 8;     // DIM_C (experts)
static constexpr int HD = 256;   // hidden width

__device__ __forceinline__ unsigned short f2bf(float f) {
  __hip_bfloat16 b = __float2bfloat16(f);
  unsigned short u;
  __builtin_memcpy(&u, &b, 2);
  return u;
}

// Pack W1/W2 into MFMA-fragment order for mfma_f32_32x32x16_bf16 so the hot
// kernel's operand loads are single fully-coalesced 1KB-per-wave bf16x8 loads.
// Fragment layout (A and B operands): lane l holds 8 contiguous k at
// k = 8*(l>>5)+e, with m|n = l&31 (exact 32x32 analog of the verified
// 16x16x32 pattern used by the previous working kernel).
//
// W2F slot (c, fg=ct*16+step, l): value = W2[c][k=step*16+(l>>5)*8+e][n=ct*32+(l&31)]
// W1F slot (c, fg=mt*4+ks,  l): value = W1[c][s=ks*16+(l>>5)*8+e][h=mt*32+(l&31)]
__global__ __launch_bounds__(256) void prep_frags(
    const float* __restrict__ W1, const float* __restrict__ W2,
    unsigned short* __restrict__ W1F, unsigned short* __restrict__ W2F)
{
  const int g = blockIdx.x * 256 + threadIdx.x;
  if (blockIdx.x < 256) {          // W2F: 8 experts x 128 frag-groups x 64 lanes
    const int c  = g >> 13, rem = g & 8191;
    const int fg = rem >> 6, l = rem & 63;
    const int ct = fg >> 4, stp = fg & 15;
    const int k0 = stp * 16 + (l >> 5) * 8;
    const int n  = ct * 32 + (l & 31);
    const float* src = W2 + ((size_t)c * 256 + k0) * 256 + n;
    unsigned short* dst = W2F + (size_t)c * 65536 + (size_t)(fg * 64 + l) * 8;
    #pragma unroll
    for (int e = 0; e < 8; ++e) dst[e] = f2bf(src[(size_t)e * 256]);
  } else {                         // W1F: 8 experts x 32 frag-groups x 64 lanes
    const int gg = g - 65536;
    const int c  = gg >> 11, rem = gg & 2047;
    const int fg = rem >> 6, l = rem & 63;
    const int mt = fg >> 2, ks = fg & 3;
    const int s0 = ks * 16 + (l >> 5) * 8;
    const int h  = mt * 32 + (l & 31);
    const float* src = W1 + ((size_t)c * 64 + s0) * 256 + h;
    unsigned short* dst = W1F + (size_t)c * 16384 + (size_t)(fg * 64 + l) * 8;
    #pragma unroll
    for (int e = 0; e < 8; ++e) dst[e] = f2bf(src[(size_t)e * 256]);
  }
}

// One block: 256 batch rows x 1 expert; 4 waves x 64 rows. 32x32x16 MFMA.
// ZERO barriers: phase-2 W2 operands come straight from L2 (fragment-packed,
// coalesced), h1 transpose uses a 5KB wave-private LDS buffer with lgkmcnt
// guards only. Expert-major grid (c=blockIdx>>8): the 8 expert-blocks of one
// st tile land on the same XCD (tile%8), so st is HBM-fetched once; W1F/W2F
// (1MB total) replicate into every XCD's L2.
__global__ __launch_bounds__(256, 2) void moe_fused(
    const float* __restrict__ st,
    const unsigned short* __restrict__ W1F,
    const unsigned short* __restrict__ W2F,
    const float* __restrict__ b1,
    const float* __restrict__ b2,
    const float* __restrict__ W3,
    const float* __restrict__ b3,
    float* __restrict__ out)
{
  constexpr int LDB = 40;   // bf16 pitch: 32 hidden + 8 pad (80B rows, 16B-mult)
  __shared__ __align__(16) unsigned short sW[4 * 64 * LDB];  // 20480 B total

  const int tid  = threadIdx.x;
  const int lane = tid & 63;
  const int wv   = tid >> 6;
  const int l31  = lane & 31;
  const int h5   = lane >> 5;
  const int c    = blockIdx.x >> 8;
  const int row0 = (blockIdx.x & 255) * 256;
  const int wrow = row0 + wv * 64;
  unsigned short* sw = sW + wv * (64 * LDB);   // wave-private

  const unsigned short* W1c = W1F + (size_t)c * 16384;
  const unsigned short* W2c = W2F + (size_t)c * 65536;

  // ---- phase-1 B frags: wave's 64 st rows (fp32->bf16), direct from global ----
  bf16x8 bB[4][2];   // [ks][nt]
  #pragma unroll
  for (int nt = 0; nt < 2; ++nt) {
    #pragma unroll
    for (int ks = 0; ks < 4; ++ks) {
      const float* rp = st + (size_t)(wrow + nt * 32 + l31) * S + ks * 16 + h5 * 8;
      float4 x = *reinterpret_cast<const float4*>(rp);
      float4 y = *reinterpret_cast<const float4*>(rp + 4);
      union { bf16x8 v; unsigned short us[8]; } pk;
      pk.us[0] = f2bf(x.x); pk.us[1] = f2bf(x.y); pk.us[2] = f2bf(x.z); pk.us[3] = f2bf(x.w);
      pk.us[4] = f2bf(y.x); pk.us[5] = f2bf(y.y); pk.us[6] = f2bf(y.z); pk.us[7] = f2bf(y.w);
      bB[ks][nt] = pk.v;
    }
  }

  // ---- phase 1: h1^T = W1^T @ st^T, one 32-hidden tile at a time.
  // D (col=batch=l31, row=hidden reg pattern) -> bias+relu -> bf16 -> sW ->
  // read back as phase-2 A-frags (m=batch=l31, k=hidden). Wave-private.
  bf16x8 aF[2][16];   // [rt][k-step] phase-2 A-frags, 128 VGPRs
  #pragma unroll
  for (int mt = 0; mt < 8; ++mt) {
    f32x16 acc0 = {}, acc1 = {};
    #pragma unroll
    for (int ks = 0; ks < 4; ++ks) {
      bf16x8 aW = *reinterpret_cast<const bf16x8*>(
          W1c + (size_t)((mt * 4 + ks) * 64 + lane) * 8);
      acc0 = __builtin_amdgcn_mfma_f32_32x32x16_bf16(aW, bB[ks][0], acc0, 0, 0, 0);
      acc1 = __builtin_amdgcn_mfma_f32_32x32x16_bf16(aW, bB[ks][1], acc1, 0, 0, 0);
    }
    f32x4 bias[4];
    #pragma unroll
    for (int gq = 0; gq < 4; ++gq)
      bias[gq] = *reinterpret_cast<const f32x4*>(
          b1 + c * HD + mt * 32 + 8 * gq + 4 * h5);
    #pragma unroll
    for (int nt = 0; nt < 2; ++nt) {
      const f32x16& A = nt ? acc1 : acc0;
      #pragma unroll
      for (int gq = 0; gq < 4; ++gq) {   // D rows 8*gq+4*h5 .. +3 (contiguous)
        ushort4 pk;
        float v0 = A[4*gq+0] + bias[gq][0]; v0 = v0 > 0.f ? v0 : 0.f;
        float v1 = A[4*gq+1] + bias[gq][1]; v1 = v1 > 0.f ? v1 : 0.f;
        float v2 = A[4*gq+2] + bias[gq][2]; v2 = v2 > 0.f ? v2 : 0.f;
        float v3 = A[4*gq+3] + bias[gq][3]; v3 = v3 > 0.f ? v3 : 0.f;
        pk.x = f2bf(v0); pk.y = f2bf(v1); pk.z = f2bf(v2); pk.w = f2bf(v3);
        *reinterpret_cast<ushort4*>(
            sw + (nt * 32 + l31) * LDB + 8 * gq + 4 * h5) = pk;
      }
    }
    __asm__ __volatile__("s_waitcnt lgkmcnt(0)" ::: "memory");
    #pragma unroll
    for (int rt = 0; rt < 2; ++rt) {
      aF[rt][2*mt]   = *reinterpret_cast<const bf16x8*>(
          sw + (rt * 32 + l31) * LDB + 8 * h5);
      aF[rt][2*mt+1] = *reinterpret_cast<const bf16x8*>(
          sw + (rt * 32 + l31) * LDB + 16 + 8 * h5);
    }
    __asm__ __volatile__("s_waitcnt lgkmcnt(0)" ::: "memory");  // WAR guard
  }

  // ---- phase-2/3 scalars ----
  float b2v[8], w3v[8];
  #pragma unroll
  for (int ct = 0; ct < 8; ++ct) {
    b2v[ct] = b2[c * HD + ct * 32 + l31];
    w3v[ct] = W3[c * HD + ct * 32 + l31];
  }
  const float bb3 = b3[c];

  // ---- phase 2+3: d = relu(h1 @ W2 + b2) . W3; B-frags straight from L2 ----
  float dacc0[16], dacc1[16];
  #pragma unroll
  for (int r = 0; r < 16; ++r) { dacc0[r] = 0.f; dacc1[r] = 0.f; }

  #pragma unroll
  for (int ct = 0; ct < 8; ++ct) {
    f32x16 acc0 = {}, acc1 = {};
    #pragma unroll
    for (int s2 = 0; s2 < 16; ++s2) {
      bf16x8 bF = *reinterpret_cast<const bf16x8*>(
          W2c + (size_t)((ct * 16 + s2) * 64 + lane) * 8);
      acc0 = __builtin_amdgcn_mfma_f32_32x32x16_bf16(aF[0][s2], bF, acc0, 0, 0, 0);
      acc1 = __builtin_amdgcn_mfma_f32_32x32x16_bf16(aF[1][s2], bF, acc1, 0, 0, 0);
    }
    // fused epilogue: relu(h2+b2) dot W3 (lane's n-col = ct*32+l31)
    #pragma unroll
    for (int r = 0; r < 16; ++r) {
      float v0 = acc0[r] + b2v[ct]; v0 = v0 > 0.f ? v0 : 0.f; dacc0[r] += v0 * w3v[ct];
      float v1 = acc1[r] + b2v[ct]; v1 = v1 > 0.f ? v1 : 0.f; dacc1[r] += v1 * w3v[ct];
    }
  }

  // ---- reduce over the 32 n-lanes (xor net stays within each half) ----
  #pragma unroll
  for (int r = 0; r < 16; ++r) {
    float v0 = dacc0[r], v1 = dacc1[r];
    v0 += __shfl_xor(v0, 1);  v1 += __shfl_xor(v1, 1);
    v0 += __shfl_xor(v0, 2);  v1 += __shfl_xor(v1, 2);
    v0 += __shfl_xor(v0, 4);  v1 += __shfl_xor(v1, 4);
    v0 += __shfl_xor(v0, 8);  v1 += __shfl_xor(v1, 8);
    v0 += __shfl_xor(v0, 16); v1 += __shfl_xor(v1, 16);
    dacc0[r] = v0; dacc1[r] = v1;
  }

  if (l31 == 0) {   // lanes 0 and 32 write (h5 splits the row groups)
    #pragma unroll
    for (int r = 0; r < 16; ++r) {
      const int rr = (r & 3) + 8 * (r >> 2) + 4 * h5;   // D row within 32-tile
      out[(size_t)(wrow + rr) * C + c]      = dacc0[r] + bb3;
      out[(size_t)(wrow + 32 + rr) * C + c] = dacc1[r] + bb3;
    }
  }
}

extern "C" void kernel_launch(void* const* d_in, const int* in_sizes, int n_in,
                              void* d_out, int out_size, void* d_ws, size_t ws_size,
                              hipStream_t stream)
{
  const float* st = (const float*)d_in[0];
  const float* W1 = (const float*)d_in[1];
  const float* b1 = (const float*)d_in[2];
  const float* W2 = (const float*)d_in[3];
  const float* b2 = (const float*)d_in[4];
  const float* W3 = (const float*)d_in[5];
  const float* b3 = (const float*)d_in[6];
  float* out = (float*)d_out;

  unsigned short* W1F = (unsigned short*)d_ws;         // 131072 bf16
  unsigned short* W2F = W1F + C * HD * S;              // 524288 bf16

  prep_frags<<<dim3(320), dim3(256), 0, stream>>>(W1, W2, W1F, W2F);
  moe_fused<<<dim3(2048), dim3(256), 0, stream>>>(st, W1F, W2F, b1, b2, W3, b3, out);
}

// Round 3
// 194.579 us; speedup vs baseline: 1.3583x; 1.3583x over previous
//
#include <hip/hip_runtime.h>
#include <hip/hip_bf16.h>

typedef __bf16 bf16x8 __attribute__((ext_vector_type(8)));
typedef float  f32x4  __attribute__((ext_vector_type(4)));
typedef float  f32x16 __attribute__((ext_vector_type(16)));

static constexpr int S  = 64;    // DIM_S
static constexpr int C  = 8;     // DIM_C (experts)
static constexpr int HD = 256;   // hidden width

__device__ __forceinline__ unsigned short f2bf(float f) {
  __hip_bfloat16 b = __float2bfloat16(f);
  unsigned short u;
  __builtin_memcpy(&u, &b, 2);
  return u;
}

// async global->LDS DMA, 16 B per lane; lds dest = wave-uniform base + lane*16
__device__ __forceinline__ void gl2lds16(const void* g, void* l) {
  __builtin_amdgcn_global_load_lds(
      (const __attribute__((address_space(1))) unsigned int*)g,
      (__attribute__((address_space(3))) unsigned int*)l, 16, 0, 0);
}

// Pack W1/W2 into MFMA-fragment order for mfma_f32_32x32x16_bf16.
// Fragment layout (A and B operands): lane l holds 8 contiguous k at
// k = 8*(l>>5)+e, with m|n = l&31.  (Layouts HW-validated: round-2 kernel
// using exactly these mappings passed refcheck.)
// W2F slot (c, fg=ct*16+stp, l): value = W2[c][k=stp*16+(l>>5)*8+e][n=ct*32+(l&31)]
// W1F slot (c, fg=mt*4+ks,  l): value = W1[c][s=ks*16+(l>>5)*8+e][h=mt*32+(l&31)]
__global__ __launch_bounds__(256) void prep_frags(
    const float* __restrict__ W1, const float* __restrict__ W2,
    unsigned short* __restrict__ W1F, unsigned short* __restrict__ W2F)
{
  const int g = blockIdx.x * 256 + threadIdx.x;
  if (blockIdx.x < 256) {          // W2F: 8 experts x 128 frag-groups x 64 lanes
    const int c  = g >> 13, rem = g & 8191;
    const int fg = rem >> 6, l = rem & 63;
    const int ct = fg >> 4, stp = fg & 15;
    const int k0 = stp * 16 + (l >> 5) * 8;
    const int n  = ct * 32 + (l & 31);
    const float* src = W2 + ((size_t)c * 256 + k0) * 256 + n;
    unsigned short* dst = W2F + (size_t)c * 65536 + (size_t)(fg * 64 + l) * 8;
    #pragma unroll
    for (int e = 0; e < 8; ++e) dst[e] = f2bf(src[(size_t)e * 256]);
  } else {                         // W1F: 8 experts x 32 frag-groups x 64 lanes
    const int gg = g - 65536;
    const int c  = gg >> 11, rem = gg & 2047;
    const int fg = rem >> 6, l = rem & 63;
    const int mt = fg >> 2, ks = fg & 3;
    const int s0 = ks * 16 + (l >> 5) * 8;
    const int h  = mt * 32 + (l & 31);
    const float* src = W1 + ((size_t)c * 64 + s0) * 256 + h;
    unsigned short* dst = W1F + (size_t)c * 16384 + (size_t)(fg * 64 + l) * 8;
    #pragma unroll
    for (int e = 0; e < 8; ++e) dst[e] = f2bf(src[(size_t)e * 256]);
  }
}

// Persistent-style: 256 blocks (1/CU) x 512 threads (8 waves x 64 batch rows).
// One expert per block; W2F (128KB bf16) DMA'd into LDS ONCE, then 4 tile-jobs
// of 512 rows run with ZERO further barriers (sW2 read-only, all else
// wave-private).  h1 D-layout -> phase-2 A-frag transpose done in-register via
// v_cvt_pk_bf16_f32 + v_permlane32_swap_b32 (no LDS, no lgkmcnt round-trip).
// Job mapping: XCD x = blk&7 runs experts 0..7 on the same batch tiles ->
// st L2-shared within an XCD; W2F replicates into each XCD's L2 once.
__global__ __launch_bounds__(512, 2) void moe_fused(
    const float* __restrict__ st,
    const unsigned short* __restrict__ W1F,
    const unsigned short* __restrict__ W2F,
    const float* __restrict__ b1,
    const float* __restrict__ b2,
    const float* __restrict__ W3,
    const float* __restrict__ b3,
    float* __restrict__ out)
{
  __shared__ __align__(16) unsigned short sW2[HD * HD];   // 131072 B

  const int tid  = threadIdx.x;
  const int lane = tid & 63;
  const int wv   = tid >> 6;          // 0..7
  const int l31  = lane & 31;
  const int h5   = lane >> 5;

  const int b    = blockIdx.x;
  const int x    = b & 7;             // XCD (round-robin assumption; perf-only)
  const int m    = b >> 3;
  const int c    = m & 7;             // expert
  const int sgrp = m >> 3;            // batch stream 0..3

  const unsigned short* W1c = W1F + (size_t)c * 16384;
  const unsigned short* W2c = W2F + (size_t)c * 65536;

  // ---- one-time DMA: whole W2F[c] -> LDS (linear, 1KB per wave-slot) ----
  #pragma unroll
  for (int it = 0; it < 16; ++it) {
    const int slot = it * 8 + wv;          // 128 slots x 1024 B
    gl2lds16(W2c + slot * 512 + lane * 8, sW2 + slot * 512);
  }

  // ---- per-block scalars (expert-fixed: hoisted out of the job loop) ----
  float b2v[8], w3v[8];
  #pragma unroll
  for (int ct = 0; ct < 8; ++ct) {
    b2v[ct] = b2[c * HD + ct * 32 + l31];
    w3v[ct] = W3[c * HD + ct * 32 + l31];
  }
  const float bb3 = b3[c];

  bool need_bar = true;

  for (int ji = 0; ji < 4; ++ji) {
    const int tile = x * 16 + sgrp * 4 + ji;    // 0..127, bijective per expert
    const int wrow = tile * 512 + wv * 64;

    // ---- phase-1 B frags: wave's 64 st rows (fp32->bf16), from global ----
    bf16x8 bB[4][2];   // [ks][nt]
    #pragma unroll
    for (int nt = 0; nt < 2; ++nt) {
      #pragma unroll
      for (int ks = 0; ks < 4; ++ks) {
        const float* rp = st + (size_t)(wrow + nt * 32 + l31) * S + ks * 16 + h5 * 8;
        float4 xx = *reinterpret_cast<const float4*>(rp);
        float4 yy = *reinterpret_cast<const float4*>(rp + 4);
        union { bf16x8 v; unsigned short us[8]; } pk;
        pk.us[0] = f2bf(xx.x); pk.us[1] = f2bf(xx.y); pk.us[2] = f2bf(xx.z); pk.us[3] = f2bf(xx.w);
        pk.us[4] = f2bf(yy.x); pk.us[5] = f2bf(yy.y); pk.us[6] = f2bf(yy.z); pk.us[7] = f2bf(yy.w);
        bB[ks][nt] = pk.v;
      }
    }

    // ---- phase 1: h1^T = W1^T @ st^T; D -> bias/relu -> in-register
    // transpose to phase-2 A-frags via cvt_pk + permlane32_swap ----
    bf16x8 aF[2][16];   // [rt][k-step], 128 VGPRs
    #pragma unroll
    for (int mt = 0; mt < 8; ++mt) {
      f32x16 acc0 = {}, acc1 = {};
      #pragma unroll
      for (int ks = 0; ks < 4; ++ks) {
        bf16x8 aW = *reinterpret_cast<const bf16x8*>(
            W1c + (size_t)((mt * 4 + ks) * 64 + lane) * 8);
        acc0 = __builtin_amdgcn_mfma_f32_32x32x16_bf16(aW, bB[ks][0], acc0, 0, 0, 0);
        acc1 = __builtin_amdgcn_mfma_f32_32x32x16_bf16(aW, bB[ks][1], acc1, 0, 0, 0);
      }
      f32x4 bias[4];
      #pragma unroll
      for (int gq = 0; gq < 4; ++gq)
        bias[gq] = *reinterpret_cast<const f32x4*>(
            b1 + c * HD + mt * 32 + 8 * gq + 4 * h5);

      // D reg 4g+j = hidden 8g+4h5+j (col = batch = l31).  Phase-2 A-frag
      // (16-k step t within mt): e = hidden 16t+8h5+e.  After half-swap:
      //   swap(X0,Y0): X0 -> e01 of t0, Y0 -> e45 of t0   (X=G0, Y=G1 packs)
      //   swap(X1,Y1): X1 -> e23,       Y1 -> e67
      //   swap(Z0,W0)/(Z1,W1): same for t1 with G2/G3.
      #pragma unroll
      for (int rt = 0; rt < 2; ++rt) {
        const f32x16& A = rt ? acc1 : acc0;
        unsigned d[8];
        #pragma unroll
        for (int p = 0; p < 8; ++p) {
          float v0 = A[2 * p]     + bias[p >> 1][2 * (p & 1)];
          float v1 = A[2 * p + 1] + bias[p >> 1][2 * (p & 1) + 1];
          v0 = v0 > 0.f ? v0 : 0.f;
          v1 = v1 > 0.f ? v1 : 0.f;
          __asm__("v_cvt_pk_bf16_f32 %0, %1, %2" : "=v"(d[p]) : "v"(v0), "v"(v1));
        }
        __asm__("v_permlane32_swap_b32 %0, %1" : "+v"(d[0]), "+v"(d[2]));
        __asm__("v_permlane32_swap_b32 %0, %1" : "+v"(d[1]), "+v"(d[3]));
        __asm__("v_permlane32_swap_b32 %0, %1" : "+v"(d[4]), "+v"(d[6]));
        __asm__("v_permlane32_swap_b32 %0, %1" : "+v"(d[5]), "+v"(d[7]));
        union { unsigned u[4]; bf16x8 v; } f0, f1;
        f0.u[0] = d[0]; f0.u[1] = d[1]; f0.u[2] = d[2]; f0.u[3] = d[3];
        f1.u[0] = d[4]; f1.u[1] = d[5]; f1.u[2] = d[6]; f1.u[3] = d[7];
        aF[rt][2 * mt]     = f0.v;
        aF[rt][2 * mt + 1] = f1.v;
      }
    }

    if (need_bar) {        // W2 DMA landed (vmcnt(0) drain + all waves)
      __syncthreads();
      need_bar = false;
    }

    // ---- phase 2+3: d = relu(h1 @ W2 + b2) . W3; B from LDS-resident W2 ----
    float dacc0[16], dacc1[16];
    #pragma unroll
    for (int r = 0; r < 16; ++r) { dacc0[r] = 0.f; dacc1[r] = 0.f; }

    #pragma unroll
    for (int ct = 0; ct < 8; ++ct) {
      f32x16 acc0 = {}, acc1 = {};
      #pragma unroll
      for (int s2 = 0; s2 < 16; ++s2) {
        bf16x8 bF = *reinterpret_cast<const bf16x8*>(
            sW2 + (size_t)((ct * 16 + s2) * 64 + lane) * 8);
        acc0 = __builtin_amdgcn_mfma_f32_32x32x16_bf16(aF[0][s2], bF, acc0, 0, 0, 0);
        acc1 = __builtin_amdgcn_mfma_f32_32x32x16_bf16(aF[1][s2], bF, acc1, 0, 0, 0);
      }
      #pragma unroll
      for (int r = 0; r < 16; ++r) {
        float v0 = acc0[r] + b2v[ct]; v0 = v0 > 0.f ? v0 : 0.f; dacc0[r] += v0 * w3v[ct];
        float v1 = acc1[r] + b2v[ct]; v1 = v1 > 0.f ? v1 : 0.f; dacc1[r] += v1 * w3v[ct];
      }
    }

    // ---- reduce over 32 n-lanes (xor net stays within each half) ----
    #pragma unroll
    for (int r = 0; r < 16; ++r) {
      float v0 = dacc0[r], v1 = dacc1[r];
      v0 += __shfl_xor(v0, 1);  v1 += __shfl_xor(v1, 1);
      v0 += __shfl_xor(v0, 2);  v1 += __shfl_xor(v1, 2);
      v0 += __shfl_xor(v0, 4);  v1 += __shfl_xor(v1, 4);
      v0 += __shfl_xor(v0, 8);  v1 += __shfl_xor(v1, 8);
      v0 += __shfl_xor(v0, 16); v1 += __shfl_xor(v1, 16);
      dacc0[r] = v0; dacc1[r] = v1;
    }

    if (l31 == 0) {   // lanes 0 and 32 write (h5 splits the row groups)
      #pragma unroll
      for (int r = 0; r < 16; ++r) {
        const int rr = (r & 3) + 8 * (r >> 2) + 4 * h5;   // D row in 32-tile
        out[(size_t)(wrow + rr) * C + c]      = dacc0[r] + bb3;
        out[(size_t)(wrow + 32 + rr) * C + c] = dacc1[r] + bb3;
      }
    }
  }
}

extern "C" void kernel_launch(void* const* d_in, const int* in_sizes, int n_in,
                              void* d_out, int out_size, void* d_ws, size_t ws_size,
                              hipStream_t stream)
{
  const float* st = (const float*)d_in[0];
  const float* W1 = (const float*)d_in[1];
  const float* b1 = (const float*)d_in[2];
  const float* W2 = (const float*)d_in[3];
  const float* b2 = (const float*)d_in[4];
  const float* W3 = (const float*)d_in[5];
  const float* b3 = (const float*)d_in[6];
  float* out = (float*)d_out;

  unsigned short* W1F = (unsigned short*)d_ws;         // 131072 bf16
  unsigned short* W2F = W1F + C * HD * S;              // 524288 bf16

  prep_frags<<<dim3(320), dim3(256), 0, stream>>>(W1, W2, W1F, W2F);
  moe_fused<<<dim3(256), dim3(512), 0, stream>>>(st, W1F, W2F, b1, b2, W3, b3, out);
}